// Round 1
// baseline (320.162 us; speedup 1.0000x reference)
//
#include <hip/hip_runtime.h>
#include <stdint.h>

#define Bn 4
#define Cn 512
#define Tn 4096
#define Kn 256
#define Nall 768

typedef __attribute__((ext_vector_type(8))) short bf16x8;
typedef __attribute__((ext_vector_type(4))) float f32x4;

__device__ __forceinline__ unsigned short f2bf(float f) {
  union { float f; unsigned int u; } v; v.f = f;
  unsigned int r = v.u + 0x7fffu + ((v.u >> 16) & 1u);
  return (unsigned short)(r >> 16);
}

__device__ __forceinline__ void gload_lds16(const void* g, void* l) {
  auto gp = reinterpret_cast<const __attribute__((address_space(1))) unsigned int*>(
      reinterpret_cast<uintptr_t>(g));
  auto lp = reinterpret_cast<__attribute__((address_space(3))) unsigned int*>(
      static_cast<unsigned int>(reinterpret_cast<uintptr_t>(l)));
  __builtin_amdgcn_global_load_lds(gp, lp, 16, 0, 0);
}

__device__ __forceinline__ f32x4 mfma16(bf16x8 a, bf16x8 b, f32x4 c) {
  return __builtin_amdgcn_mfma_f32_16x16x32_bf16(a, b, c, 0, 0, 0);
}

// ---------------------------------------------------------------------------
// prep_x: fp32 passthrough copy into out rows [0,512) + transpose to x_t bf16 (B,T,C)
// ---------------------------------------------------------------------------
__global__ __launch_bounds__(256) void prep_x_kernel(const float* __restrict__ x,
    float* __restrict__ out, unsigned short* __restrict__ xt) {
  const int tt = blockIdx.x, cc = blockIdx.y, b = blockIdx.z;
  __shared__ unsigned short tile[64][66];   // pad 2: transposed reads ~conflict-free
  const int tid = threadIdx.x;
#pragma unroll
  for (int e = 0; e < 4; ++e) {
    int f = e * 256 + tid;                  // float4 index 0..1023
    int row = f >> 4, c4 = f & 15;          // row = c-local, 16 float4 per row
    size_t gi = ((size_t)(b * Cn + cc * 64 + row)) * Tn + tt * 64 + c4 * 4;
    float4 v = *(const float4*)(x + gi);
    size_t go = ((size_t)(b * Nall + cc * 64 + row)) * Tn + tt * 64 + c4 * 4;
    *(float4*)(out + go) = v;               // exact passthrough
    tile[row][c4 * 4 + 0] = f2bf(v.x);
    tile[row][c4 * 4 + 1] = f2bf(v.y);
    tile[row][c4 * 4 + 2] = f2bf(v.z);
    tile[row][c4 * 4 + 3] = f2bf(v.w);
  }
  __syncthreads();
#pragma unroll
  for (int e = 0; e < 2; ++e) {
    int f = e * 256 + tid;                  // 8-elem chunk index 0..511
    int trow = f >> 3, cv = f & 7;
    bf16x8 vv;
#pragma unroll
    for (int j = 0; j < 8; ++j) vv[j] = (short)tile[cv * 8 + j][trow];
    *(bf16x8*)(xt + ((size_t)(b * Tn) + tt * 64 + trow) * Cn + cc * 64 + cv * 8) = vv;
  }
}

// ---------------------------------------------------------------------------
// prep_w: W^T bf16 (768 x 512), n: 0..255=q 256..511=k 512..767=v ; bias concat
// ---------------------------------------------------------------------------
__global__ __launch_bounds__(256) void prep_w_kernel(const float* __restrict__ Wq,
    const float* __restrict__ Wk, const float* __restrict__ Wv,
    const float* __restrict__ bq, const float* __restrict__ bk, const float* __restrict__ bv,
    unsigned short* __restrict__ wt, float* __restrict__ bias) {
  int idx = blockIdx.x * 256 + threadIdx.x;   // < 768*512
  int n = idx >> 9, c = idx & 511;
  const float* W = (n < 256) ? Wq : ((n < 512) ? Wk : Wv);
  wt[idx] = f2bf(W[c * 256 + (n & 255)]);
  if (idx < Nall) {
    const float* bb = (idx < 256) ? bq : ((idx < 512) ? bk : bv);
    bias[idx] = bb[idx & 255];
  }
}

// ---------------------------------------------------------------------------
// qkv_gemm: per batch  out[t,n] = sum_c x_t[t,c] * W^T[n,c] + bias[n]
// 128x128 tile, BK=32, 4 waves (2x2), 16x16x32 bf16 MFMA (m97 structure).
// Epilogue: q -> qb[t][n]; k -> kb[t][n ^ ((t&7)<<3)] (pre-swizzled);
//           v -> vt[n][(t&~63)|((t&63)^((n&7)<<3))] (transposed + pre-swizzled)
// ---------------------------------------------------------------------------
__global__ __launch_bounds__(256) void qkv_gemm_kernel(const unsigned short* __restrict__ xt,
    const unsigned short* __restrict__ wt, const float* __restrict__ bias,
    unsigned short* __restrict__ qb, unsigned short* __restrict__ kb,
    unsigned short* __restrict__ vt) {
  const int t0 = blockIdx.x * 128, n0 = blockIdx.y * 128, b = blockIdx.z;
  __shared__ char at[8192];    // A tile [128][32] bf16, 64B rows
  __shared__ char bt[8192];    // B^T tile [128][32] bf16
  const int tid = threadIdx.x, w = tid >> 6, lane = tid & 63, g = lane >> 4, lr = lane & 15;
  const int wm = w >> 1, wn = w & 1;
  f32x4 acc[4][4];
#pragma unroll
  for (int i = 0; i < 4; ++i)
#pragma unroll
    for (int j = 0; j < 4; ++j) acc[i][j] = (f32x4){0.f, 0.f, 0.f, 0.f};

  const unsigned short* xtp = xt + ((size_t)b * Tn + t0) * Cn;
  for (int c0 = 0; c0 < Cn; c0 += 32) {
    __syncthreads();
#pragma unroll
    for (int i = 0; i < 2; ++i) {
      int off = i * 4096 + w * 1024 + lane * 16;   // byte offset (src mapping)
      int row = off >> 6, col = off & 63;
      gload_lds16(xtp + (size_t)row * Cn + c0 + (col >> 1), at + i * 4096 + w * 1024);
      gload_lds16(wt + (size_t)(n0 + row) * Cn + c0 + (col >> 1), bt + i * 4096 + w * 1024);
    }
    __syncthreads();
    bf16x8 af[4], bfr[4];
#pragma unroll
    for (int mt = 0; mt < 4; ++mt)
      af[mt] = *(const bf16x8*)(at + (wm * 64 + mt * 16 + lr) * 64 + g * 16);
#pragma unroll
    for (int nt = 0; nt < 4; ++nt)
      bfr[nt] = *(const bf16x8*)(bt + (wn * 64 + nt * 16 + lr) * 64 + g * 16);
#pragma unroll
    for (int mt = 0; mt < 4; ++mt)
#pragma unroll
      for (int nt = 0; nt < 4; ++nt)
        acc[mt][nt] = mfma16(af[mt], bfr[nt], acc[mt][nt]);
  }
  // epilogue: D[row=4g+r][col=lr]
#pragma unroll
  for (int nt = 0; nt < 4; ++nt) {
    int n = n0 + wn * 64 + nt * 16 + lr;
    float bval = bias[n];
#pragma unroll
    for (int mt = 0; mt < 4; ++mt) {
#pragma unroll
      for (int r = 0; r < 4; ++r) {
        int t = t0 + wm * 64 + mt * 16 + g * 4 + r;
        unsigned short h = f2bf(acc[mt][nt][r] + bval);
        if (n < 256) {
          qb[((size_t)(b * Tn) + t) * Kn + n] = h;
        } else if (n < 512) {
          int nc = n - 256;
          kb[((size_t)(b * Tn) + t) * Kn + (nc ^ ((t & 7) << 3))] = h;
        } else {
          int vc = n - 512;
          int tl = t & 63;
          vt[((size_t)(b * Kn) + vc) * Tn + (t & ~63) + (tl ^ ((vc & 7) << 3))] = h;
        }
      }
    }
  }
}

// ---------------------------------------------------------------------------
// attn: flash causal attention. 1 block = 64 q-rows (4 waves x 16), BS=64.
// K tile [64][512B] + V^T tile [256][128B] in LDS (both arrive pre-swizzled
// via linear global_load_lds). P round-trips through wave-private kbuf slice.
// ---------------------------------------------------------------------------
__global__ __launch_bounds__(256) void attn_kernel(const unsigned short* __restrict__ qb,
    const unsigned short* __restrict__ kb, const unsigned short* __restrict__ vt,
    float* __restrict__ out) {
  const int tile = blockIdx.x, b = blockIdx.y;
  const int qt0 = tile * 64;
  __shared__ char kbuf[32768];
  __shared__ char vbuf[32768];
  const int tid = threadIdx.x, w = tid >> 6, lane = tid & 63, g = lane >> 4, lr = lane & 15;
  const float SCL = 0.09016844005555521f;   // log2(e)/sqrt(256)

  // Q fragments in registers: rows qt0+16w+lr, full K-dim
  const unsigned short* qrow = qb + ((size_t)(b * Tn) + qt0 + w * 16 + lr) * Kn;
  bf16x8 qf[8];
#pragma unroll
  for (int kc = 0; kc < 8; ++kc) qf[kc] = *(const bf16x8*)(qrow + kc * 32 + g * 8);

  f32x4 o[16];
#pragma unroll
  for (int nt = 0; nt < 16; ++nt) o[nt] = (f32x4){0.f, 0.f, 0.f, 0.f};
  float m2[4], lsum[4];
#pragma unroll
  for (int r = 0; r < 4; ++r) { m2[r] = -1e30f; lsum[r] = 0.f; }

  const unsigned short* kbp = kb + (size_t)(b * Tn) * Kn;
  const unsigned short* vtp = vt + (size_t)(b * Kn) * Tn;
  const int nsteps = tile + 1;

  for (int s = 0; s < nsteps; ++s) {
    const int s0 = s * 64;
    __syncthreads();   // prev-step LDS reads (incl. P region) complete
#pragma unroll
    for (int i = 0; i < 8; ++i) {
      int off = i * 4096 + w * 1024 + lane * 16;
      { int row = off >> 9, col = off & 511;
        gload_lds16(kbp + (size_t)(s0 + row) * Kn + (col >> 1), kbuf + i * 4096 + w * 1024); }
      { int row = off >> 7, col = off & 127;
        gload_lds16(vtp + (size_t)row * Tn + s0 + (col >> 1), vbuf + i * 4096 + w * 1024); }
    }
    __syncthreads();   // staging drained (vmcnt 0 before barrier)

    // QK^T : S[16q][64s]
    f32x4 sfr[4];
#pragma unroll
    for (int ct = 0; ct < 4; ++ct) sfr[ct] = (f32x4){0.f, 0.f, 0.f, 0.f};
#pragma unroll
    for (int kc = 0; kc < 8; ++kc) {
#pragma unroll
      for (int ct = 0; ct < 4; ++ct) {
        int srow = ct * 16 + lr;
        bf16x8 kf = *(const bf16x8*)(kbuf + srow * 512 +
                                     ((kc * 64 + g * 16) ^ ((srow & 7) << 4)));
        sfr[ct] = mfma16(qf[kc], kf, sfr[ct]);
      }
    }

    // online softmax (base-2), rows r: t = qt0+16w+4g+r
    float sv[4][4];
    const bool diag = (s0 == qt0);
#pragma unroll
    for (int ct = 0; ct < 4; ++ct)
#pragma unroll
      for (int r = 0; r < 4; ++r) {
        float v = sfr[ct][r] * SCL;
        if (diag) {
          int trow = qt0 + w * 16 + g * 4 + r;
          int scol = s0 + ct * 16 + lr;
          if (scol > trow) v = -1e30f;
        }
        sv[ct][r] = v;
      }
    float mt_[4];
#pragma unroll
    for (int r = 0; r < 4; ++r)
      mt_[r] = fmaxf(fmaxf(sv[0][r], sv[1][r]), fmaxf(sv[2][r], sv[3][r]));
#pragma unroll
    for (int d = 1; d < 16; d <<= 1)
#pragma unroll
      for (int r = 0; r < 4; ++r)
        mt_[r] = fmaxf(mt_[r], __shfl_xor(mt_[r], d, 64));
    float al[4], rs[4];
#pragma unroll
    for (int r = 0; r < 4; ++r) {
      float mn = fmaxf(m2[r], mt_[r]);
      al[r] = __builtin_amdgcn_exp2f(m2[r] - mn);
      m2[r] = mn;
      rs[r] = 0.f;
    }
    unsigned short ph[4][4];
#pragma unroll
    for (int ct = 0; ct < 4; ++ct)
#pragma unroll
      for (int r = 0; r < 4; ++r) {
        float p = __builtin_amdgcn_exp2f(sv[ct][r] - m2[r]);
        rs[r] += p;
        ph[ct][r] = f2bf(p);
      }
#pragma unroll
    for (int d = 1; d < 16; d <<= 1)
#pragma unroll
      for (int r = 0; r < 4; ++r)
        rs[r] += __shfl_xor(rs[r], d, 64);
#pragma unroll
    for (int r = 0; r < 4; ++r) lsum[r] = lsum[r] * al[r] + rs[r];
#pragma unroll
    for (int nt = 0; nt < 16; ++nt)
#pragma unroll
      for (int r = 0; r < 4; ++r) o[nt][r] *= al[r];

    __syncthreads();   // all waves done reading kbuf -> safe to reuse as P store
    char* pbw = kbuf + w * 2048;   // wave-private P [16][64] bf16, swizzled
#pragma unroll
    for (int ct = 0; ct < 4; ++ct)
#pragma unroll
      for (int r = 0; r < 4; ++r) {
        int row = g * 4 + r;
        int colb = (ct * 16 + lr) * 2;
        *(unsigned short*)(pbw + row * 128 + (colb ^ ((row & 7) << 4))) = ph[ct][r];
      }
    bf16x8 pa[2];
#pragma unroll
    for (int kc2 = 0; kc2 < 2; ++kc2)
      pa[kc2] = *(const bf16x8*)(pbw + lr * 128 +
                                 ((kc2 * 64 + g * 16) ^ ((lr & 7) << 4)));
#pragma unroll
    for (int nt = 0; nt < 16; ++nt) {
      int vrow = nt * 16 + lr;
#pragma unroll
      for (int kc2 = 0; kc2 < 2; ++kc2) {
        bf16x8 vf = *(const bf16x8*)(vbuf + vrow * 128 +
                                     ((kc2 * 64 + g * 16) ^ ((vrow & 7) << 4)));
        o[nt] = mfma16(pa[kc2], vf, o[nt]);
      }
    }
  }

  float inv[4];
#pragma unroll
  for (int r = 0; r < 4; ++r) inv[r] = 1.0f / lsum[r];
  float* outp = out + ((size_t)(b * Nall) + 512) * Tn;
#pragma unroll
  for (int nt = 0; nt < 16; ++nt) {
#pragma unroll
    for (int r = 0; r < 4; ++r) {
      int n = nt * 16 + lr;
      int t = qt0 + w * 16 + g * 4 + r;
      outp[(size_t)n * Tn + t] = o[nt][r] * inv[r];
    }
  }
}

// ---------------------------------------------------------------------------
extern "C" void kernel_launch(void* const* d_in, const int* in_sizes, int n_in,
                              void* d_out, int out_size, void* d_ws, size_t ws_size,
                              hipStream_t stream) {
  const float* x  = (const float*)d_in[0];
  const float* Wq = (const float*)d_in[1];
  const float* bq = (const float*)d_in[2];
  const float* Wk = (const float*)d_in[3];
  const float* bk = (const float*)d_in[4];
  const float* Wv = (const float*)d_in[5];
  const float* bv = (const float*)d_in[6];
  float* out = (float*)d_out;
  char* ws = (char*)d_ws;

  unsigned short* xt = (unsigned short*)(ws);                 // 16,777,216 B
  unsigned short* wt = (unsigned short*)(ws + 16777216);      //    786,432 B
  float*        bias = (float*)(ws + 17563648);               //      3,072 B
  unsigned short* qb = (unsigned short*)(ws + 17566720);      //  8,388,608 B
  unsigned short* kb = (unsigned short*)(ws + 25955328);      //  8,388,608 B
  unsigned short* vt = (unsigned short*)(ws + 34343936);      //  8,388,608 B (ends 42,732,544)

  prep_w_kernel<<<1536, 256, 0, stream>>>(Wq, Wk, Wv, bq, bk, bv, wt, bias);
  prep_x_kernel<<<dim3(64, 8, 4), 256, 0, stream>>>(x, out, xt);
  qkv_gemm_kernel<<<dim3(32, 6, 4), 256, 0, stream>>>(xt, wt, bias, qb, kb, vt);
  attn_kernel<<<dim3(64, 4), 256, 0, stream>>>(qb, kb, vt, out);
}